// Round 6
// baseline (213.332 us; speedup 1.0000x reference)
//
#include <hip/hip_runtime.h>
#include <stdint.h>

// proj = einsum('bit,ih->tbh', x, W); scan: h=relu(p+0.8h(1-y)); y=thr(h+b,1).
// B=64, K=512, T=512, H=1024 fp32. Output: final y (64x1024).
//
// R6: register-direct fragments. Pre-pass stores fp16 hi/lo in MFMA fragment
// order; each wave loads its A/B fragments straight from global memory as
// coalesced 1KB global_load_dwordx4 (lane addr = l15*64B + lq*16B) -> no A/B
// LDS, no staging writes, NO k-loop barriers or vmcnt(0) drains (the R5
// profile showed the 51 us above the 49 us MFMA floor was exactly these).
// Numerics (validated R1/R2/R5): hi=fp16(64v), lo=fp16(64v-hi), single fp32
// acc over 3 MFMA passes, P=acc/4096. 8 waves, 64x128 wave tiles,
// 256t x 256h block, grid 64x4 = 1 block/CU. LDS = P only (67.6 KB).

#define NB 64
#define NK 512
#define NT 512
#define NH 1024

#define TB 256     // t per block tile
#define HB 256     // h per block tile
#define KK 32      // k per step

typedef _Float16 h8_t __attribute__((ext_vector_type(8)));
typedef float    f4_t __attribute__((ext_vector_type(4)));

// ---- pre-pass: fp32 [bb*512 + k][C] -> fp16 hi/lo in fragment order
// [bb*16+kt][c][32] (chunk ck = k-octet, plain order; swizzle removed --
// it only served LDS banks, and R6 reads fragments from global).
__global__ __launch_bounds__(256) void split_fragorder(
    const float* __restrict__ src, _Float16* __restrict__ dhi,
    _Float16* __restrict__ dlo, int C)
{
    const int c  = threadIdx.x >> 2;   // 0..63
    const int ck = threadIdx.x & 3;    // k-octet
    const int c0 = blockIdx.x * 64;
    const int kt = blockIdx.y;
    const int bb = blockIdx.z;

    const int cg = c0 + c;
    const float* s = src + ((size_t)(bb * 512 + kt * 32 + ck * 8)) * C + cg;

    h8_t hi, lo;
    #pragma unroll
    for (int j = 0; j < 8; ++j) {
        float v = s[(size_t)j * C] * 64.0f;   // 2^6 pre-scale (keeps lo normal)
        _Float16 hh = (_Float16)v;
        hi[j] = hh;
        lo[j] = (_Float16)(v - (float)hh);    // exact residual, fp16-rounded
    }
    const size_t off = ((size_t)(bb * 16 + kt) * C + cg) * 32 + ck * 8;
    *(h8_t*)(dhi + off) = hi;
    *(h8_t*)(dlo + off) = lo;
}

// ---------------- main fused kernel ----------------
__global__ __launch_bounds__(512, 2) void fused_main(
    const _Float16* __restrict__ xhi, const _Float16* __restrict__ xlo,
    const _Float16* __restrict__ whi, const _Float16* __restrict__ wlo,
    const float* __restrict__ bias, float* __restrict__ out)
{
    __shared__ float P[2][64][132];   // 67,584 B — the only LDS

    const int tid  = threadIdx.x;
    const int lane = tid & 63;
    const int wid  = tid >> 6;     // 0..7
    const int l15  = lane & 15;
    const int lq   = lane >> 4;    // 0..3
    const int wm   = wid >> 1;     // t quarter 0..3
    const int wn   = wid & 1;      // h half 0..1

    const int b  = blockIdx.x;
    const int h0 = blockIdx.y * HB;

    // per-lane fragment offsets (halfs). Within a row-block of [rows][32]:
    // frag row = base + mi*16 + l15, chunk = lq -> off = (row)*32 + lq*8.
    // Across a wave: l15*64B + lq*16B = contiguous 1KB per dwordx4 load.
    const int aLane = (wm * 64 + l15) * 32 + lq * 8;    // + mi*512
    const int bLane = (h0 + wn * 128 + l15) * 32 + lq * 8;  // + ni*512

    float hs = 0.0f, ys = 0.0f, bv = 0.0f;
    if (tid < HB) bv = bias[h0 + tid];

    const float INV_SCALE = 1.0f / 4096.0f;   // undo 2^6 x 2^6 operand scales

    f4_t acc[4][8];

    for (int tt0 = 0; tt0 < NT; tt0 += TB) {
        #pragma unroll
        for (int mi = 0; mi < 4; ++mi)
            #pragma unroll
            for (int ni = 0; ni < 8; ++ni) {
                f4_t z = {0.f, 0.f, 0.f, 0.f};
                acc[mi][ni] = z;
            }

        for (int kt = 0; kt < NK / KK; ++kt) {
            // A fragments: x[b], rows tt0 + wm*64 + mi*16 + l15
            const _Float16* pah = xhi + ((size_t)(b * 16 + kt) * NT + tt0) * 32 + aLane;
            const _Float16* pal = xlo + ((size_t)(b * 16 + kt) * NT + tt0) * 32 + aLane;
            // B fragments: W rows h0 + wn*128 + ni*16 + l15
            const _Float16* pbh = whi + (size_t)kt * NH * 32 + bLane;
            const _Float16* pbl = wlo + (size_t)kt * NH * 32 + bLane;

            h8_t bh[8], bl[8];
            #pragma unroll
            for (int ni = 0; ni < 8; ++ni) {
                bh[ni] = *(const h8_t*)(pbh + ni * 512);
                bl[ni] = *(const h8_t*)(pbl + ni * 512);
            }
            h8_t ah[4], al[4];
            #pragma unroll
            for (int mi = 0; mi < 4; ++mi) {
                ah[mi] = *(const h8_t*)(pah + mi * 512);
                al[mi] = *(const h8_t*)(pal + mi * 512);
            }

            #pragma unroll
            for (int mi = 0; mi < 4; ++mi)
                #pragma unroll
                for (int ni = 0; ni < 8; ++ni) {
                    acc[mi][ni] = __builtin_amdgcn_mfma_f32_16x16x32_f16(ah[mi], bh[ni], acc[mi][ni], 0, 0, 0);
                    acc[mi][ni] = __builtin_amdgcn_mfma_f32_16x16x32_f16(ah[mi], bl[ni], acc[mi][ni], 0, 0, 0);
                    acc[mi][ni] = __builtin_amdgcn_mfma_f32_16x16x32_f16(al[mi], bh[ni], acc[mi][ni], 0, 0, 0);
                }
            // no barrier: fragments are private; waves sync only at epilogue
        }

        // epilogue: 4 t-subtiles x 64; both h-halves concurrently (P[0],P[1])
        #pragma unroll 1
        for (int sub = 0; sub < 4; ++sub) {
            if (wm == sub) {
                float (*Pb)[132] = P[wn];
                #pragma unroll
                for (int mi = 0; mi < 4; ++mi)
                    #pragma unroll
                    for (int ni = 0; ni < 8; ++ni)
                        #pragma unroll
                        for (int r = 0; r < 4; ++r)
                            Pb[mi * 16 + lq * 4 + r][ni * 16 + l15] = acc[mi][ni][r] * INV_SCALE;
            }
            __syncthreads();
            if (tid < HB) {
                const float (*Pb)[132] = P[tid >> 7];
                const int c = tid & 127;
                #pragma unroll 8
                for (int m = 0; m < 64; ++m) {
                    float p = Pb[m][c];
                    float pre = p + 0.8f * hs * (1.0f - ys);
                    hs = pre > 0.0f ? pre : 0.0f;
                    float z = hs + bv;
                    ys = (z > 1.0f) ? z : 0.0f;
                }
            }
            __syncthreads();   // scan done before next sub overwrites P
        }
    }

    if (tid < HB)
        out[(size_t)b * NH + h0 + tid] = ys;
}

extern "C" void kernel_launch(void* const* d_in, const int* in_sizes, int n_in,
                              void* d_out, int out_size, void* d_ws, size_t ws_size,
                              hipStream_t stream) {
    const float* x    = (const float*)d_in[0];  // [64][512][512]
    const float* W    = (const float*)d_in[1];  // [512][1024]
    const float* bias = (const float*)d_in[2];  // [1024]
    float* out = (float*)d_out;

    _Float16* xhi = (_Float16*)d_ws;
    _Float16* xlo = xhi + (size_t)NB * NK * NT;
    _Float16* whi = xlo + (size_t)NB * NK * NT;
    _Float16* wlo = whi + (size_t)NK * NH;

    split_fragorder<<<dim3(NT / 64, NK / 32, NB), 256, 0, stream>>>(x, xhi, xlo, NT);
    split_fragorder<<<dim3(NH / 64, NK / 32, 1), 256, 0, stream>>>(W, whi, wlo, NH);
    fused_main<<<dim3(NB, NH / HB), 512, 0, stream>>>(xhi, xlo, whi, wlo, bias, out);
}

// Round 7
// 194.050 us; speedup vs baseline: 1.0994x; 1.0994x over previous
//
#include <hip/hip_runtime.h>
#include <stdint.h>

// proj = einsum('bit,ih->tbh', x, W); scan: h=relu(p+0.8h(1-y)); y=thr(h+b,1).
// B=64, K=512, T=512, H=1024 fp32. Output: final y (64x1024).
//
// R7: hybrid operand routing + software-pipelined staging.
//  - R5 showed the 51us over the 49us MFMA floor = per-k-step vmcnt(0) drains
//    (stage issued then immediately drained). R6 showed all-register-direct
//    overloads the VMEM/L1 pipe (192 KB/CU/k-step @ ~64 B/cy > MFMA time).
//  - Fix: B (shared by 4 waves) via DOUBLE-BUFFERED LDS, staged one full
//    k-step ahead; A (shared by 2, half the bytes) register-direct from
//    global. One barrier per k-step; the explicit s_waitcnt(0) before it
//    drains a stage issued ~3700 cyc earlier -> nearly free.
//  - Loop shape: [drain+barrier; stage(g+1)->other buf; compute buf[g&1]].
//    WAR safe: the buffer being staged was last ds_read in iter g-1, and
//    those reads completed before this barrier (lgkmcnt drained).
// Numerics (validated R1/R2/R5): hi=fp16(64v), lo=fp16(64v-hi), single fp32
// acc over 3 MFMA passes, P=acc/4096. 8 waves, 64x128 wave tiles,
// 256t x 256h block, grid 64x4 = 1 block/CU. LDS 133 KB.

#define NB 64
#define NK 512
#define NT 512
#define NH 1024

#define TB 256     // t per block tile
#define HB 256     // h per block tile
#define KK 32      // k per step
#define NSTEP (NK / KK)            // 16 k-steps per t-tile
#define GTOT  ((NT / TB) * NSTEP)  // 32 total k-steps

typedef _Float16 h8_t __attribute__((ext_vector_type(8)));
typedef float    f4_t __attribute__((ext_vector_type(4)));

#define AS1 __attribute__((address_space(1)))
#define AS3 __attribute__((address_space(3)))

__device__ __forceinline__ void async_copy16(const _Float16* g, _Float16* l) {
    __builtin_amdgcn_global_load_lds((const AS1 uint32_t*)g, (AS3 uint32_t*)l, 16, 0, 0);
}

// explicit drain + barrier: do not trust compiler waitcnt placement across
// the loop back-edge (R3/R4 failure). The drained stage is one full compute
// phase old here, so this costs ~nothing.
__device__ __forceinline__ void wait_all_barrier() {
    __builtin_amdgcn_s_waitcnt(0);
    __syncthreads();
}

// ---- pre-pass (R5-proven, 0 bank conflicts): fp32 [bb*512+k][C] -> fp16
// hi/lo in fragment order [bb*16+kt][c][32], chunk ck at ck ^ ((c>>1)&3).
// Pre-scaled 2^6 so lo residuals stay fp16-normal.
__global__ __launch_bounds__(256) void split_fragorder(
    const float* __restrict__ src, _Float16* __restrict__ dhi,
    _Float16* __restrict__ dlo, int C)
{
    const int c  = threadIdx.x >> 2;   // 0..63
    const int ck = threadIdx.x & 3;    // k-octet
    const int c0 = blockIdx.x * 64;
    const int kt = blockIdx.y;
    const int bb = blockIdx.z;

    const int cg = c0 + c;
    const float* s = src + ((size_t)(bb * 512 + kt * 32 + ck * 8)) * C + cg;

    h8_t hi, lo;
    #pragma unroll
    for (int j = 0; j < 8; ++j) {
        float v = s[(size_t)j * C] * 64.0f;   // 2^6 pre-scale
        _Float16 hh = (_Float16)v;
        hi[j] = hh;
        lo[j] = (_Float16)(v - (float)hh);    // exact residual, fp16-rounded
    }
    const int ckp = ck ^ ((cg >> 1) & 3);
    const size_t off = ((size_t)(bb * 16 + kt) * C + cg) * 32 + ckp * 8;
    *(h8_t*)(dhi + off) = hi;
    *(h8_t*)(dlo + off) = lo;
}

// ---------------- main fused kernel ----------------
__global__ __launch_bounds__(512, 2) void fused_main(
    const _Float16* __restrict__ xhi, const _Float16* __restrict__ xlo,
    const _Float16* __restrict__ whi, const _Float16* __restrict__ wlo,
    const float* __restrict__ bias, float* __restrict__ out)
{
    __shared__ __align__(16) _Float16 Bhi[2][HB * KK];  // 2 x 16 KB
    __shared__ __align__(16) _Float16 Blo[2][HB * KK];  // 2 x 16 KB
    __shared__ float P[2][64][132];                     // 67,584 B; total 133,120

    const int tid  = threadIdx.x;
    const int lane = tid & 63;
    const int wid  = tid >> 6;     // 0..7
    const int l15  = lane & 15;
    const int lq   = lane >> 4;    // 0..3
    const int wm   = wid >> 1;     // t quarter 0..3
    const int wn   = wid & 1;      // h half 0..1

    const int b  = blockIdx.x;
    const int h0 = blockIdx.y * HB;

    // swizzled fragment offsets (halfs), matching pre-pass chunk placement
    const int sw   = (l15 >> 1) & 3;
    const int aoff = ((wm * 64 + l15) * 4 + (lq ^ sw)) * 8;   // + mi*512
    const int boff = ((wn * 128 + l15) * 4 + (lq ^ sw)) * 8;  // + ni*512

    float hs = 0.0f, ys = 0.0f, bv = 0.0f;
    if (tid < HB) bv = bias[h0 + tid];

    const float INV_SCALE = 1.0f / 4096.0f;   // undo 2^6 x 2^6 operand scales

    // stage W k-slice for step g into buffer g&1 (32 KB total, 4 copies/thread)
    auto stage = [&](int g) {
        const int kt = g & (NSTEP - 1);
        const _Float16* gh = whi + ((size_t)kt * NH + h0) * 32;
        const _Float16* gl = wlo + ((size_t)kt * NH + h0) * 32;
        _Float16* dh = &Bhi[g & 1][0];
        _Float16* dl = &Blo[g & 1][0];
        #pragma unroll
        for (int c = 0; c < 2; ++c) {
            const int ch = tid + c * 512;
            async_copy16(gh + ch * 8, dh + ch * 8);
            async_copy16(gl + ch * 8, dl + ch * 8);
        }
    };

    f4_t acc[4][8];

    stage(0);

    for (int g = 0; g < GTOT; ++g) {
        if ((g & (NSTEP - 1)) == 0) {
            #pragma unroll
            for (int mi = 0; mi < 4; ++mi)
                #pragma unroll
                for (int ni = 0; ni < 8; ++ni) {
                    f4_t z = {0.f, 0.f, 0.f, 0.f};
                    acc[mi][ni] = z;
                }
        }

        wait_all_barrier();            // publishes buf[g&1] (staged 1 iter ago)
        if (g + 1 < GTOT) stage(g + 1);  // into the other buffer (WAR-safe)

        // ---- compute step g ----
        const int tt0 = (g >> 4) * TB;
        const int kt  = g & (NSTEP - 1);
        const int cur = g & 1;

        // A fragments register-direct from global (coalesced 1KB dwordx4)
        const _Float16* pah = xhi + ((size_t)(b * 16 + kt) * NT + tt0) * 32 + aoff;
        const _Float16* pal = xlo + ((size_t)(b * 16 + kt) * NT + tt0) * 32 + aoff;
        h8_t ah[4], al[4];
        #pragma unroll
        for (int mi = 0; mi < 4; ++mi) {
            ah[mi] = *(const h8_t*)(pah + mi * 512);
            al[mi] = *(const h8_t*)(pal + mi * 512);
        }
        // B fragments from LDS (swizzled, conflict-free per R5)
        h8_t bh[8], bl[8];
        #pragma unroll
        for (int ni = 0; ni < 8; ++ni) {
            bh[ni] = *(const h8_t*)(&Bhi[cur][boff + ni * 512]);
            bl[ni] = *(const h8_t*)(&Blo[cur][boff + ni * 512]);
        }

        #pragma unroll
        for (int mi = 0; mi < 4; ++mi)
            #pragma unroll
            for (int ni = 0; ni < 8; ++ni) {
                acc[mi][ni] = __builtin_amdgcn_mfma_f32_16x16x32_f16(ah[mi], bh[ni], acc[mi][ni], 0, 0, 0);
                acc[mi][ni] = __builtin_amdgcn_mfma_f32_16x16x32_f16(ah[mi], bl[ni], acc[mi][ni], 0, 0, 0);
                acc[mi][ni] = __builtin_amdgcn_mfma_f32_16x16x32_f16(al[mi], bh[ni], acc[mi][ni], 0, 0, 0);
            }

        // ---- t-tile boundary: epilogue + scan ----
        if ((g & (NSTEP - 1)) == NSTEP - 1) {
            #pragma unroll 1
            for (int sub = 0; sub < 4; ++sub) {
                if (wm == sub) {
                    float (*Pb)[132] = P[wn];
                    #pragma unroll
                    for (int mi = 0; mi < 4; ++mi)
                        #pragma unroll
                        for (int ni = 0; ni < 8; ++ni)
                            #pragma unroll
                            for (int r = 0; r < 4; ++r)
                                Pb[mi * 16 + lq * 4 + r][ni * 16 + l15] = acc[mi][ni][r] * INV_SCALE;
                }
                __syncthreads();
                if (tid < HB) {
                    const float (*Pb)[132] = P[tid >> 7];
                    const int c = tid & 127;
                    #pragma unroll 8
                    for (int m = 0; m < 64; ++m) {
                        float p = Pb[m][c];
                        float pre = p + 0.8f * hs * (1.0f - ys);
                        hs = pre > 0.0f ? pre : 0.0f;
                        float z = hs + bv;
                        ys = (z > 1.0f) ? z : 0.0f;
                    }
                }
                __syncthreads();   // scan done before next sub overwrites P
            }
        }
    }

    if (tid < HB)
        out[(size_t)b * NH + h0 + tid] = ys;
}

extern "C" void kernel_launch(void* const* d_in, const int* in_sizes, int n_in,
                              void* d_out, int out_size, void* d_ws, size_t ws_size,
                              hipStream_t stream) {
    const float* x    = (const float*)d_in[0];  // [64][512][512]
    const float* W    = (const float*)d_in[1];  // [512][1024]
    const float* bias = (const float*)d_in[2];  // [1024]
    float* out = (float*)d_out;

    _Float16* xhi = (_Float16*)d_ws;
    _Float16* xlo = xhi + (size_t)NB * NK * NT;
    _Float16* whi = xlo + (size_t)NB * NK * NT;
    _Float16* wlo = whi + (size_t)NK * NH;

    split_fragorder<<<dim3(NT / 64, NK / 32, NB), 256, 0, stream>>>(x, xhi, xlo, NT);
    split_fragorder<<<dim3(NH / 64, NK / 32, 1), 256, 0, stream>>>(W, whi, wlo, NH);
    fused_main<<<dim3(NB, NH / HB), 512, 0, stream>>>(xhi, xlo, whi, wlo, bias, out);
}